// Round 4
// baseline (566.757 us; speedup 1.0000x reference)
//
#include <hip/hip_runtime.h>
#include <hip/hip_bf16.h>

// Problem constants (B=4,T=2048,M=1024,E=8,H=4096) — fp32 in/out
#define S_TOK 8192
#define MDIM  1024
#define EXP   8
#define HDIM  4096
#define CAP   1024   // s // E, capacity_factor = 1.0

typedef __attribute__((ext_vector_type(8))) short short8;
typedef __attribute__((ext_vector_type(4))) float floatx4;

#define BARRIER() asm volatile("s_barrier" ::: "memory")
#define WAITV6()  asm volatile("s_waitcnt vmcnt(6)" ::: "memory")
#define WAITV0()  asm volatile("s_waitcnt vmcnt(0)" ::: "memory")
#define SCHEDB()  __builtin_amdgcn_sched_barrier(0)

__device__ __forceinline__ unsigned short f2b(float f) {
    union { float f; unsigned int i; } v; v.f = f;
    unsigned int r = v.i + 0x7fffu + ((v.i >> 16) & 1u);  // RNE
    return (unsigned short)(r >> 16);
}

// async global->LDS, 16B per lane, wave-uniform LDS base (HW adds lane*16)
__device__ __forceinline__ void gl2lds16(const unsigned short* g, unsigned short* l) {
    __builtin_amdgcn_global_load_lds(
        (const __attribute__((address_space(1))) unsigned int*)g,
        (__attribute__((address_space(3))) unsigned int*)l,
        16, 0, 0);
}

// ---------------- LDS-free register transpose: 64x256 tile per 256-thr block
// Reads: 8 x 256B contiguous segments / instruction (fp32 rows).
// Writes: 8 x 128B full-line segments / instruction (bf16 columns).
__device__ __forceinline__ void transpose_tile_reg(
    const float* __restrict__ src, unsigned short* __restrict__ dst,
    int R, int C, int R0, int C0)
{
    const int t  = threadIdx.x;
    const int rg = t & 7;    // row group: rows R0 + rg*8 .. +7
    const int cg = t >> 3;   // col group: cols C0 + cg*8 .. +7 (32 groups)
    const float* p = src + (size_t)(R0 + rg * 8) * C + C0 + cg * 8;
    float v[8][8];
#pragma unroll
    for (int i = 0; i < 8; ++i) {
        *(float4*)&v[i][0] = *(const float4*)(p + (size_t)i * C);
        *(float4*)&v[i][4] = *(const float4*)(p + (size_t)i * C + 4);
    }
    unsigned short* q = dst + (size_t)(C0 + cg * 8) * R + R0 + rg * 8;
#pragma unroll
    for (int j = 0; j < 8; ++j) {
        unsigned short o[8];
#pragma unroll
        for (int i = 0; i < 8; ++i) o[i] = f2b(v[i][j]);
        *(int4*)(q + (size_t)j * R) = *(const int4*)o;
    }
}

// ---------------- Dispatch A: gate (blocks 0..2047) + w1 transpose (2048..4095)
// gate: fp32 logits/softmax/argmax (must match np ref); also writes xb16.
// w1 [e][1024][4096] fp32 -> W1T [e][4096][1024] bf16, 64x256 tiles.
__global__ __launch_bounds__(256) void gate_fused(
    const float* __restrict__ x, const float* __restrict__ wg,
    float* __restrict__ gates8, int* __restrict__ token_expert,
    unsigned short* __restrict__ xb16,
    const float* __restrict__ w1, unsigned short* __restrict__ W1T)
{
    const int b = blockIdx.x;
    if (b >= 2048) {
        // ---- w1 transpose: per expert 16 row-tiles x 16 col-tiles
        const int i = b - 2048;
        const int e = i >> 8, rem = i & 255;
        const int bx = rem & 15, by = rem >> 4;
        transpose_tile_reg(w1 + (size_t)e * MDIM * HDIM, W1T + (size_t)e * MDIM * HDIM,
                           MDIM, HDIM, by * 64, bx * 256);
        return;
    }

    const int wave = threadIdx.x >> 6, lane = threadIdx.x & 63;
    const int s = b * 4 + wave;

    const float* xr = x + (size_t)s * MDIM + lane * 16;
    float xv[16];
#pragma unroll
    for (int q = 0; q < 4; ++q) *(float4*)(xv + q * 4) = *(const float4*)(xr + q * 4);

    {
        unsigned short bv[16];
#pragma unroll
        for (int j = 0; j < 16; ++j) bv[j] = f2b(xv[j]);
        int4* dst = (int4*)(xb16 + (size_t)s * MDIM + lane * 16);
        dst[0] = ((const int4*)bv)[0];
        dst[1] = ((const int4*)bv)[1];
    }

    float acc[EXP];
#pragma unroll
    for (int e = 0; e < EXP; ++e) acc[e] = 0.f;
    const int m0 = lane * 16;
#pragma unroll
    for (int j = 0; j < 16; ++j) {
        const float xm = xv[j];
        const float* wr = wg + (size_t)(m0 + j) * EXP;
        float4 w0 = *(const float4*)(wr);
        float4 w1v = *(const float4*)(wr + 4);
        acc[0] += xm * w0.x; acc[1] += xm * w0.y; acc[2] += xm * w0.z; acc[3] += xm * w0.w;
        acc[4] += xm * w1v.x; acc[5] += xm * w1v.y; acc[6] += xm * w1v.z; acc[7] += xm * w1v.w;
    }
#pragma unroll
    for (int e = 0; e < EXP; ++e) {
#pragma unroll
        for (int off = 32; off > 0; off >>= 1)
            acc[e] += __shfl_down(acc[e], off);
    }
    if (lane == 0) {
        float mx = acc[0]; int idx = 0;
#pragma unroll
        for (int e = 1; e < EXP; ++e) if (acc[e] > mx) { mx = acc[e]; idx = e; }
        float g[EXP]; float sum = 0.f;
#pragma unroll
        for (int e = 0; e < EXP; ++e) { g[e] = expf(acc[e] - mx); sum += g[e]; }
        float inv = 1.f / sum;
#pragma unroll
        for (int e = 0; e < EXP; ++e) gates8[(size_t)s * EXP + e] = g[e] * inv;
        token_expert[s] = idx;
    }
}

// ---------------- Dispatch B: scan (block 0) + out-zero (1..2048) + w2T -----
__global__ __launch_bounds__(256) void mega_prep(
    const float* __restrict__ gates8, const int* __restrict__ token_expert,
    int* __restrict__ slot_token, float* __restrict__ slot_gate,
    float* __restrict__ laux_out,
    const float* __restrict__ w2, unsigned short* __restrict__ W2T,
    float* __restrict__ outz)
{
    __shared__ int   cntS[256 * EXP];
    __shared__ float fsumS[256 * EXP];

    const int b = blockIdx.x;
    const int t = threadIdx.x;

    if (b == 0) {
        // ---------------- scan ----------------
        for (int i = t; i < EXP * CAP; i += 256) slot_token[i] = -1;

        int local[EXP];
#pragma unroll
        for (int e = 0; e < EXP; ++e) local[e] = 0;
        const int s0 = t * 32;
        for (int j = 0; j < 32; ++j) local[token_expert[s0 + j]]++;

        int incl[EXP];
#pragma unroll
        for (int e = 0; e < EXP; ++e) { incl[e] = local[e]; cntS[t * EXP + e] = incl[e]; }
        __syncthreads();
        // Hillis-Steele inclusive scan over 256 entries (8 steps)
        for (int d = 1; d < 256; d <<= 1) {
            int add[EXP];
            if (t >= d) {
#pragma unroll
                for (int e = 0; e < EXP; ++e) add[e] = cntS[(t - d) * EXP + e];
            }
            __syncthreads();
            if (t >= d) {
#pragma unroll
                for (int e = 0; e < EXP; ++e) { incl[e] += add[e]; cntS[t * EXP + e] = incl[e]; }
            }
            __syncthreads();
        }

        int off[EXP];
#pragma unroll
        for (int e = 0; e < EXP; ++e) off[e] = incl[e] - local[e];
        for (int j = 0; j < 32; ++j) {
            int s = s0 + j;
            int e = token_expert[s];
            int loc = off[e]++;
            if (loc < CAP) {
                int slot = e * CAP + loc;
                slot_token[slot] = s;
                slot_gate[slot]  = gates8[(size_t)s * EXP + e];
            }
        }

        float ms[EXP];
#pragma unroll
        for (int e = 0; e < EXP; ++e) ms[e] = 0.f;
        for (int j = 0; j < 32; ++j) {
            const float* g = gates8 + (size_t)(s0 + j) * EXP;
#pragma unroll
            for (int e = 0; e < EXP; ++e) ms[e] += g[e];
        }
#pragma unroll
        for (int e = 0; e < EXP; ++e) fsumS[t * EXP + e] = ms[e];
        __syncthreads();
        for (int st = 128; st > 0; st >>= 1) {
            if (t < st) {
#pragma unroll
                for (int e = 0; e < EXP; ++e) fsumS[t * EXP + e] += fsumS[(t + st) * EXP + e];
            }
            __syncthreads();
        }
        if (t == 0) {
            float l = 0.f;
#pragma unroll
            for (int e = 0; e < EXP; ++e)
                l += (fsumS[e] / (float)S_TOK) * ((float)cntS[255 * EXP + e] / (float)S_TOK);
            laux_out[0] = l * (float)EXP;
        }
        return;
    }

    if (b <= 2048) {
        // ---------------- zero out ----------------
        float4* p = (float4*)(outz + (size_t)(b - 1) * 4096 + t * 16);
        const float4 z = {0.f, 0.f, 0.f, 0.f};
        p[0] = z; p[1] = z; p[2] = z; p[3] = z;
        return;
    }

    // ---------------- w2 transpose: per expert 64 row-tiles x 4 col-tiles ---
    const int i = b - 2049;
    const int e = i >> 8, rem = i & 255;
    const int bx = rem & 3, by = rem >> 2;
    transpose_tile_reg(w2 + (size_t)e * MDIM * HDIM, W2T + (size_t)e * MDIM * HDIM,
                       HDIM, MDIM, by * 64, bx * 256);
}

// ---------------- standalone reg transpose (narrow-ws mid path) ------------
__global__ __launch_bounds__(256) void transpose_reg(
    const float* __restrict__ src, unsigned short* __restrict__ dst,
    int R, int C, int ct)
{
    const int i = blockIdx.x;
    const int e = i >> 8, rem = i & 255;
    const int bx = rem % ct, by = rem / ct;
    transpose_tile_reg(src + (size_t)e * R * C, dst + (size_t)e * R * C,
                       R, C, by * 64, bx * 256);
}

// ============ pipelined expert GEMM (T1+T2+T3+T4+T5), 2 phases/tile ========
// out[CAP, N] = A[CAP, K] @ BT[N, K]^T per expert (blockIdx.z), bf16 MFMA.
// BM=256 BN=128 BK=64, 512 threads (8 waves as 2M x 4N), per-wave out 128x32.
// 3-deep LDS tile ring (144 KiB dynamic): tile t+2 staged into buffer freed
// by tile t-1 -> counted vmcnt(6) once per tile, never 0 in main loop.
// 2 phases/tile, 16 MFMA per phase (m201 cluster size):
//   ph A: ds_read B-all + A-half0; stage A0-A3; MFMA m0 x {n0,n1}
//   ph B: ds_read A-half1;         stage B0,B1; MFMA m1 x {n0,n1}
// T2 swizzle: k-slot ^= row&7 via pre-swizzled global source (linear glds
// dest) + swizzled ds_read (rule 21).
template<int KT, int N, bool SCATTER, bool GATHER>
__global__ __launch_bounds__(512, 2) void ffn_gemm_8p(
    const unsigned short* __restrict__ Ag, const unsigned short* __restrict__ BT,
    void* __restrict__ Outv,
    const int* __restrict__ slot_token, const float* __restrict__ slot_gate)
{
    constexpr int K   = KT * 64;
    constexpr int NBX = N / 128;
    constexpr int NWG = NBX * (CAP / 256);   // per-expert x-grid; NWG%8==0

    extern __shared__ __align__(16) unsigned short sm[];
    unsigned short* Abuf = sm;               // 3 * 16384 ushorts (96 KiB)
    unsigned short* Bbuf = sm + 3 * 16384;   // 3 *  8192 ushorts (48 KiB)

    const int e    = blockIdx.z;
    const int orig = blockIdx.x;
    // T1: bijective XCD swizzle (NWG divisible by 8)
    const int logical = (orig & 7) * (NWG >> 3) + (orig >> 3);
    const int nb = (logical % NBX) * 128;
    const int ib = (logical / NBX) * 256;

    const int tid  = threadIdx.x;
    const int lane = tid & 63, wave = tid >> 6;
    const int quad = lane >> 4, l15 = lane & 15;
    const int wm = wave >> 2, wn = wave & 3;

    // ---- staging addressing (per thread): chunk = 64 rows x 64 k = 8 KiB.
    // thread covers LDS bytes [tid*16, +16): row = tid/8, phys slot = tid&7.
    // T2: fetch logical slot = phys ^ (row&7) so swizzled data lands linearly.
    const int rr   = tid >> 3;                 // row within chunk (0..63)
    const int slot = (tid & 7) ^ (rr & 7);     // logical k-slot (8 bf16 each)

    const unsigned short* sA0;
    const unsigned short* sA1;
    const unsigned short* sA2;
    const unsigned short* sA3;
    if (GATHER) {
        const int base = e * CAP + ib + rr;
        int t0 = slot_token[base];
        int t1 = slot_token[base + 64];
        int t2 = slot_token[base + 128];
        int t3 = slot_token[base + 192];
        sA0 = Ag + (size_t)(t0 < 0 ? 0 : t0) * K + slot * 8;
        sA1 = Ag + (size_t)(t1 < 0 ? 0 : t1) * K + slot * 8;
        sA2 = Ag + (size_t)(t2 < 0 ? 0 : t2) * K + slot * 8;
        sA3 = Ag + (size_t)(t3 < 0 ? 0 : t3) * K + slot * 8;
    } else {
        sA0 = Ag + (size_t)(e * CAP + ib + rr) * K + slot * 8;
        sA1 = sA0 + (size_t)64 * K;
        sA2 = sA0 + (size_t)128 * K;
        sA3 = sA0 + (size_t)192 * K;
    }
    const unsigned short* Bsrc = BT + ((size_t)e * N + nb + rr) * K + slot * 8;

    auto stageA = [&](int buf, int t, const unsigned short* s, int ca) {
        gl2lds16(s + t * 64, Abuf + buf * 16384 + ca * 4096 + wave * 512);
    };
    auto stageB = [&](int buf, int t, int cb) {
        gl2lds16(Bsrc + (size_t)cb * 64 * K + t * 64,
                 Bbuf + buf * 8192 + cb * 4096 + wave * 512);
    };

    // ---- fragment read addressing (swizzled): off = row*64 + ((ks*4+quad)^(row&7))*8
    const int sx  = l15 & 7;                   // row&7 == l15&7 for all frag rows
    const int ko0 = ((0 + quad) ^ sx) * 8;     // ks = 0
    const int ko1 = ((4 + quad) ^ sx) * 8;     // ks = 1
    const int arow = wm * 128 + l15;           // + mh*64 + fm*16
    const int brow = wn * 32 + l15;            // + fn*16

    floatx4 acc[8][2];
#pragma unroll
    for (int i = 0; i < 8; ++i)
#pragma unroll
        for (int j = 0; j < 2; ++j)
            acc[i][j] = (floatx4){0.f, 0.f, 0.f, 0.f};

    // ---- prologue: stage tiles 0 and 1 fully (6 loads each per wave)
    stageA(0, 0, sA0, 0); stageA(0, 0, sA1, 1); stageA(0, 0, sA2, 2); stageA(0, 0, sA3, 3);
    stageB(0, 0, 0); stageB(0, 0, 1);
    stageA(1, 1, sA0, 0); stageA(1, 1, sA1, 1); stageA(1, 1, sA2, 2); stageA(1, 1, sA3, 3);
    stageB(1, 1, 0); stageB(1, 1, 1);
    WAITV6();   // tile 0's 6 loads done; tile 1's may be in flight
    BARRIER();

    int buf = 0;
    for (int t = 0; t < KT; ++t) {
        const int nbuf = (buf >= 1) ? buf - 1 : 2;   // (buf+2)%3
        const bool st  = (t + 2 < KT);

        // ---------- phase A: read B(all)+A-half0; stage A0-A3; MFMA m0 (16)
        short8 brg[2][2];
#pragma unroll
        for (int fn = 0; fn < 2; ++fn) {
            const int row = brow + fn * 16;
            brg[fn][0] = *(const short8*)&Bbuf[buf * 8192 + row * 64 + ko0];
            brg[fn][1] = *(const short8*)&Bbuf[buf * 8192 + row * 64 + ko1];
        }
        short8 aA[8];
#pragma unroll
        for (int fm = 0; fm < 4; ++fm) {
            const int row = arow + fm * 16;
            aA[fm * 2 + 0] = *(const short8*)&Abuf[buf * 16384 + row * 64 + ko0];
            aA[fm * 2 + 1] = *(const short8*)&Abuf[buf * 16384 + row * 64 + ko1];
        }
        if (st) {
            stageA(nbuf, t + 2, sA0, 0); stageA(nbuf, t + 2, sA1, 1);
            stageA(nbuf, t + 2, sA2, 2); stageA(nbuf, t + 2, sA3, 3);
        }
        BARRIER(); SCHEDB();
        __builtin_amdgcn_s_setprio(1);
#pragma unroll
        for (int fm = 0; fm < 4; ++fm) {
            acc[fm][0] = __builtin_amdgcn_mfma_f32_16x16x32_bf16(aA[fm*2+0], brg[0][0], acc[fm][0], 0, 0, 0);
            acc[fm][0] = __builtin_amdgcn_mfma_f32_16x16x32_bf16(aA[fm*2+1], brg[0][1], acc[fm][0], 0, 0, 0);
            acc[fm][1] = __builtin_amdgcn_mfma_f32_16x16x32_bf16(aA[fm*2+0], brg[1][0], acc[fm][1], 0, 0, 0);
            acc[fm][1] = __builtin_amdgcn_mfma_f32_16x16x32_bf16(aA[fm*2+1], brg[1][1], acc[fm][1], 0, 0, 0);
        }
        __builtin_amdgcn_s_setprio(0); SCHEDB(); BARRIER();

        // ---------- phase B: read A-half1; stage B0,B1; MFMA m1 (16)
        short8 aB[8];
#pragma unroll
        for (int fm = 0; fm < 4; ++fm) {
            const int row = arow + 64 + fm * 16;
            aB[fm * 2 + 0] = *(const short8*)&Abuf[buf * 16384 + row * 64 + ko0];
            aB[fm * 2 + 1] = *(const short8*)&Abuf[buf * 16384 + row * 64 + ko1];
        }
        if (st) { stageB(nbuf, t + 2, 0); stageB(nbuf, t + 2, 1); }
        BARRIER(); SCHEDB();
        __builtin_amdgcn_s_setprio(1);
#pragma unroll
        for (int fm = 0; fm < 4; ++fm) {
            acc[4+fm][0] = __builtin_amdgcn_mfma_f32_16x16x32_bf16(aB[fm*2+0], brg[0][0], acc[4+fm][0], 0, 0, 0);
            acc[4+fm][0] = __builtin_amdgcn_mfma_f32_16x16x32_bf16(aB[fm*2+1], brg[0][1], acc[4+fm][0], 0, 0, 0);
            acc[4+fm][1] = __builtin_amdgcn_mfma_f32_16x16x32_bf16(aB[fm*2+0], brg[1][0], acc[4+fm][1], 0, 0, 0);
            acc[4+fm][1] = __builtin_amdgcn_mfma_f32_16x16x32_bf16(aB[fm*2+1], brg[1][1], acc[4+fm][1], 0, 0, 0);
        }
        __builtin_amdgcn_s_setprio(0); SCHEDB();
        if (t + 1 < KT) {
            if (st) WAITV6(); else WAITV0();   // next tile's 6 loads complete
            BARRIER();
        }
        buf = (buf == 2) ? 0 : buf + 1;
    }

    // ---- epilogue: C/D layout col=lane&15, row=quad*4+reg
#pragma unroll
    for (int FM = 0; FM < 8; ++FM) {
        const int rowb = ib + wm * 128 + FM * 16 + quad * 4;
#pragma unroll
        for (int r = 0; r < 4; ++r) {
            const int gi = rowb + r;
            if (SCATTER) {
                const int slotI = e * CAP + gi;
                const int tok = slot_token[slotI];
                if (tok >= 0) {
                    const float gsc = slot_gate[slotI];
                    float* Out = (float*)Outv;
#pragma unroll
                    for (int fn = 0; fn < 2; ++fn) {
                        const int gn = nb + wn * 32 + fn * 16 + l15;
                        Out[(size_t)tok * N + gn] = gsc * acc[FM][fn][r];
                    }
                }
            } else {
                unsigned short* Out = (unsigned short*)Outv;
#pragma unroll
                for (int fn = 0; fn < 2; ++fn) {
                    const int gn = nb + wn * 32 + fn * 16 + l15;
                    Out[((size_t)e * CAP + gi) * N + gn] = f2b(fmaxf(acc[FM][fn][r], 0.f));
                }
            }
        }
    }
}

// ---------------- Kernel 2 (fallback): scan / slot assignment / l_aux ------
__global__ __launch_bounds__(256) void scan_kernel(
    const float* __restrict__ gates8, const int* __restrict__ token_expert,
    int* __restrict__ slot_token, float* __restrict__ slot_gate,
    float* __restrict__ laux_out)
{
    __shared__ int   cnt[256][EXP];
    __shared__ float fsum[256][EXP];
    __shared__ int   tot[EXP];
    const int t = threadIdx.x;

    for (int i = t; i < EXP * CAP; i += 256) slot_token[i] = -1;

    int local[EXP];
#pragma unroll
    for (int e = 0; e < EXP; ++e) local[e] = 0;
    const int s0 = t * 32;
    for (int j = 0; j < 32; ++j) local[token_expert[s0 + j]]++;
#pragma unroll
    for (int e = 0; e < EXP; ++e) cnt[t][e] = local[e];
    __syncthreads();

    if (t < EXP) {
        int run = 0;
        for (int i = 0; i < 256; ++i) { int v = cnt[i][t]; cnt[i][t] = run; run += v; }
        tot[t] = run;
    }
    __syncthreads();

    int off[EXP];
#pragma unroll
    for (int e = 0; e < EXP; ++e) off[e] = cnt[t][e];
    for (int j = 0; j < 32; ++j) {
        int s = s0 + j;
        int e = token_expert[s];
        int loc = off[e]++;
        if (loc < CAP) {
            int slot = e * CAP + loc;
            slot_token[slot] = s;
            slot_gate[slot]  = gates8[(size_t)s * EXP + e];
        }
    }

    float ms[EXP];
#pragma unroll
    for (int e = 0; e < EXP; ++e) ms[e] = 0.f;
    for (int j = 0; j < 32; ++j) {
        const float* g = gates8 + (size_t)(s0 + j) * EXP;
#pragma unroll
        for (int e = 0; e < EXP; ++e) ms[e] += g[e];
    }
#pragma unroll
    for (int e = 0; e < EXP; ++e) fsum[t][e] = ms[e];
    __syncthreads();
    for (int st = 128; st > 0; st >>= 1) {
        if (t < st) {
#pragma unroll
            for (int e = 0; e < EXP; ++e) fsum[t][e] += fsum[t + st][e];
        }
        __syncthreads();
    }
    if (t == 0) {
        float l = 0.f;
#pragma unroll
        for (int e = 0; e < EXP; ++e)
            l += (fsum[0][e] / (float)S_TOK) * ((float)tot[e] / (float)S_TOK);
        laux_out[0] = l * (float)EXP;
    }
}

// ---------------- Fallback (proven): fused-cvt GEMM ------------------------
template<int KSTEPS, int N, bool GATHER, bool SCATTER>
__global__ __launch_bounds__(256) void ffn_gemm_slow(
    const void* __restrict__ Agv, const float* __restrict__ Bg,
    void* __restrict__ Outv,
    const int* __restrict__ slot_token, const float* __restrict__ slot_gate)
{
    constexpr int K = KSTEPS * 32;
    const int e  = blockIdx.z;
    const int ib = blockIdx.y * 128;
    const int nb = blockIdx.x * 128;
    const int t  = threadIdx.x;

    __shared__ unsigned short As[128 * 40];
    __shared__ unsigned short Bs[32 * 136];

    const float* B = Bg + (size_t)e * K * N;
    const int arow  = t >> 1;
    const int ahalf = t & 1;
    const float* ArowF = nullptr;
    const unsigned short* ArowH = nullptr;
    bool avalid = true;
    if (GATHER) {
        int tok = slot_token[e * CAP + ib + arow];
        avalid = (tok >= 0);
        ArowF = (const float*)Agv + (size_t)(avalid ? tok : 0) * K;
    } else {
        ArowH = (const unsigned short*)Agv + ((size_t)e * CAP + ib + arow) * K;
    }
    const int bk  = t >> 3;
    const int bn0 = (t & 7) * 16;
    const float* Bptr = B + (size_t)bk * N + nb + bn0;

    const int lane = t & 63, wave = t >> 6;
    const int quad = lane >> 4, l15 = lane & 15;
    const int wr = wave >> 1, wc = wave & 1;

    floatx4 acc[4][4];
#pragma unroll
    for (int r = 0; r < 4; ++r)
#pragma unroll
        for (int c = 0; c < 4; ++c)
            acc[r][c] = (floatx4){0.f, 0.f, 0.f, 0.f};

    for (int kb = 0; kb < KSTEPS; ++kb) {
        const int k0 = kb * 32;
        unsigned short av[16];
        if (GATHER) {
            if (avalid) {
                const float4* p = (const float4*)(ArowF + k0 + ahalf * 16);
                float4 f0 = p[0], f1 = p[1], f2 = p[2], f3 = p[3];
                const float fa[16] = {f0.x,f0.y,f0.z,f0.w, f1.x,f1.y,f1.z,f1.w,
                                      f2.x,f2.y,f2.z,f2.w, f3.x,f3.y,f3.z,f3.w};
#pragma unroll
                for (int j = 0; j < 16; ++j) av[j] = f2b(fa[j]);
            } else {
#pragma unroll
                for (int j = 0; j < 16; ++j) av[j] = 0;
            }
        } else {
            const int4* p = (const int4*)(ArowH + k0 + ahalf * 16);
            *(int4*)(av)     = p[0];
            *(int4*)(av + 8) = p[1];
        }
        unsigned short bv[16];
        {
            const float4* q = (const float4*)(Bptr + (size_t)k0 * N);
            float4 f0 = q[0], f1 = q[1], f2 = q[2], f3 = q[3];
            const float fb[16] = {f0.x,f0.y,f0.z,f0.w, f1.x,f1.y,f1.z,f1.w,
                                  f2.x,f2.y,f2.z,f2.w, f3.x,f3.y,f3.z,f3.w};
#pragma unroll
            for (int j = 0; j < 16; ++j) bv[j] = f2b(fb[j]);
        }

        *(int4*)&As[arow * 40 + ahalf * 16]     = *(int4*)(av);
        *(int4*)&As[arow * 40 + ahalf * 16 + 8] = *(int4*)(av + 8);
        *(int4*)&Bs[bk * 136 + bn0]             = *(int4*)(bv);
        *(int4*)&Bs[bk * 136 + bn0 + 8]         = *(int4*)(bv + 8);
        __syncthreads();

        short8 af[4];
#pragma unroll
        for (int r = 0; r < 4; ++r)
            af[r] = *(const short8*)&As[(wr * 64 + r * 16 + l15) * 40 + quad * 8];
        short8 bfr[4];
#pragma unroll
        for (int c = 0; c < 4; ++c) {
#pragma unroll
            for (int j = 0; j < 8; ++j)
                bfr[c][j] = (short)Bs[(quad * 8 + j) * 136 + wc * 64 + c * 16 + l15];
        }
#pragma unroll
        for (int r = 0; r < 4; ++r)
#pragma unroll
            for (int c = 0; c < 4; ++c)
                acc[r][c] = __builtin_amdgcn_mfma_f32_16x16x32_bf16(af[r], bfr[c], acc[r][c], 0, 0, 0);
        __syncthreads();
    }

#pragma unroll
    for (int r = 0; r < 4; ++r) {
#pragma unroll
        for (int reg = 0; reg < 4; ++reg) {
            const int gi = ib + wr * 64 + r * 16 + quad * 4 + reg;
            if (SCATTER) {
                const int slot = e * CAP + gi;
                const int tok = slot_token[slot];
                if (tok >= 0) {
                    const float gsc = slot_gate[slot];
                    float* Out = (float*)Outv;
#pragma unroll
                    for (int c = 0; c < 4; ++c) {
                        const int gn = nb + wc * 64 + c * 16 + l15;
                        Out[(size_t)tok * N + gn] = gsc * acc[r][c][reg];
                    }
                }
            } else {
                unsigned short* Out = (unsigned short*)Outv;
#pragma unroll
                for (int c = 0; c < 4; ++c) {
                    const int gn = nb + wc * 64 + c * 16 + l15;
                    Out[((size_t)e * CAP + gi) * N + gn] = f2b(fmaxf(acc[r][c][reg], 0.f));
                }
            }
        }
    }
}

extern "C" void kernel_launch(void* const* d_in, const int* in_sizes, int n_in,
                              void* d_out, int out_size, void* d_ws, size_t ws_size,
                              hipStream_t stream)
{
    const float* x  = (const float*)d_in[0];   // [8192,1024] fp32
    const float* wg = (const float*)d_in[1];   // [1024,8]    fp32
    const float* w1 = (const float*)d_in[2];   // [8,1024,4096] fp32
    const float* w2 = (const float*)d_in[3];   // [8,4096,1024] fp32
    float* out = (float*)d_out;                // 8388608 out + 1 l_aux, fp32
    float* laux = out + (size_t)S_TOK * MDIM;

    char* ws = (char*)d_ws;
    float* gates8       = (float*)(ws);                 // 256 KB
    int*   token_expert = (int*)(ws + 262144);          // 32 KB
    int*   slot_token   = (int*)(ws + 294912);          // 32 KB
    float* slot_gate    = (float*)(ws + 327680);        // 32 KB
    unsigned short* xb16 = (unsigned short*)(ws + 360448);      // 16 MB
    unsigned short* h    = (unsigned short*)(ws + 17137664);    // 64 MB
    unsigned short* W1T  = (unsigned short*)(ws + 84246528);    // 64 MB
    unsigned short* W2T  = (unsigned short*)(ws + 151355392);   // 64 MB (wide only)

    const size_t FAST_NEED = 151355392ull;               // through W1T
    const size_t WIDE_NEED = 218464256ull;               // + W2T

    if (ws_size >= FAST_NEED) {
        const bool wide = (ws_size >= WIDE_NEED);

        static bool tried = false, ok8 = false;
        if (!tried) {
            tried = true;
            ok8 = (hipFuncSetAttribute((const void*)ffn_gemm_8p<16, HDIM, false, true>,
                       hipFuncAttributeMaxDynamicSharedMemorySize, 147456) == hipSuccess)
               && (hipFuncSetAttribute((const void*)ffn_gemm_8p<64, MDIM, true, false>,
                       hipFuncAttributeMaxDynamicSharedMemorySize, 147456) == hipSuccess);
        }

        // dispatch A: gate (2048 blocks) + w1 transpose (2048 blocks)
        gate_fused<<<dim3(4096), dim3(256), 0, stream>>>(
            x, wg, gates8, token_expert, xb16, w1, W1T);

        // dispatch B: scan + out-zero + w2 transpose (wide) in parallel
        const int nblk = 1 + 2048 + (wide ? 2048 : 0);
        mega_prep<<<dim3(nblk), dim3(256), 0, stream>>>(
            gates8, token_expert, slot_token, slot_gate, laux,
            w2, wide ? W2T : W1T, out);

        if (ok8) {
            ffn_gemm_8p<16, HDIM, false, true><<<dim3((HDIM/128)*(CAP/256), 1, EXP), dim3(512), 147456, stream>>>(
                xb16, W1T, h, slot_token, slot_gate);
            if (!wide)
                transpose_reg<<<dim3(2048), dim3(256), 0, stream>>>(w2, W1T, HDIM, MDIM, MDIM / 256);
            ffn_gemm_8p<64, MDIM, true, false><<<dim3((MDIM/128)*(CAP/256), 1, EXP), dim3(512), 147456, stream>>>(
                h, wide ? W2T : W1T, out, slot_token, slot_gate);
        } else {
            // proven fallback: fused-cvt GEMMs straight from fp32 weights
            ffn_gemm_slow<32, HDIM, true, false><<<dim3(HDIM / 128, CAP / 128, EXP), dim3(256), 0, stream>>>(
                x, w1, h, slot_token, slot_gate);
            ffn_gemm_slow<128, MDIM, false, true><<<dim3(MDIM / 128, CAP / 128, EXP), dim3(256), 0, stream>>>(
                h, w2, out, slot_token, slot_gate);
        }
    } else {
        hipMemsetAsync(d_out, 0, (size_t)out_size * 4, stream);
        gate_fused<<<dim3(2048), dim3(256), 0, stream>>>(
            x, wg, gates8, token_expert, xb16, w1, (unsigned short*)h);
        scan_kernel<<<dim3(1), dim3(256), 0, stream>>>(gates8, token_expert, slot_token, slot_gate, laux);
        unsigned short* hs = (unsigned short*)(ws + 360448);    // 64 MB
        ffn_gemm_slow<32, HDIM, true, false><<<dim3(HDIM / 128, CAP / 128, EXP), dim3(256), 0, stream>>>(
            x, w1, hs, slot_token, slot_gate);
        ffn_gemm_slow<128, MDIM, false, true><<<dim3(MDIM / 128, CAP / 128, EXP), dim3(256), 0, stream>>>(
            hs, w2, out, slot_token, slot_gate);
    }
}

// Round 5
// 546.399 us; speedup vs baseline: 1.0373x; 1.0373x over previous
//
#include <hip/hip_runtime.h>
#include <hip/hip_bf16.h>

// Problem constants (B=4,T=2048,M=1024,E=8,H=4096) — fp32 in/out
#define S_TOK 8192
#define MDIM  1024
#define EXP   8
#define HDIM  4096
#define CAP   1024   // s // E, capacity_factor = 1.0

typedef __attribute__((ext_vector_type(8))) short short8;
typedef __attribute__((ext_vector_type(4))) float floatx4;

#define BARRIER() asm volatile("s_barrier" ::: "memory")
#define WAITV6()  asm volatile("s_waitcnt vmcnt(6)" ::: "memory")
#define WAITV0()  asm volatile("s_waitcnt vmcnt(0)" ::: "memory")
#define SCHEDB()  __builtin_amdgcn_sched_barrier(0)

__device__ __forceinline__ unsigned short f2b(float f) {
    union { float f; unsigned int i; } v; v.f = f;
    unsigned int r = v.i + 0x7fffu + ((v.i >> 16) & 1u);  // RNE
    return (unsigned short)(r >> 16);
}

// async global->LDS, 16B per lane, wave-uniform LDS base (HW adds lane*16)
__device__ __forceinline__ void gl2lds16(const unsigned short* g, unsigned short* l) {
    __builtin_amdgcn_global_load_lds(
        (const __attribute__((address_space(1))) unsigned int*)g,
        (__attribute__((address_space(3))) unsigned int*)l,
        16, 0, 0);
}

// ---------------- LDS pair-pack transpose: 256 rows x 128 cols per block ---
// src fp32 [R][C] (R0..R0+255, C0..C0+127) -> dst bf16 [C][R] transposed.
// Phase 1: 512B-contiguous global reads per src row; row-pairs packed into
//   uint (lo=r, hi=r+1); b128 LDS writes, XOR-swizzled at 16B granularity.
// Phase 2: b32 LDS column reads (2-way bank spread = free); 256B-contiguous
//   global write runs, 512B per output DRAM-row visit (vs 128B before).
// U layout: U[rp=0..127][c=0..127] uint, with c-block XOR SW(rp)=((rp>>2)&7)<<2.
__device__ __forceinline__ void transpose_tile_lds(
    const float* __restrict__ src, unsigned short* __restrict__ dst,
    int R, int C, int R0, int C0, unsigned int* U)
{
    const int t = threadIdx.x;
    // ---- phase 1
    const int cu  = (t & 31) * 4;   // uint-col base (= source col base)
    const int rph = t >> 5;         // 0..7
#pragma unroll
    for (int i = 0; i < 16; ++i) {
        const int rp = i * 8 + rph;                 // row-pair 0..127
        const int r0 = R0 + rp * 2;
        const float4 a = *(const float4*)(src + (size_t)r0 * C + C0 + cu);
        const float4 b = *(const float4*)(src + (size_t)(r0 + 1) * C + C0 + cu);
        unsigned int u[4];
        u[0] = (unsigned int)f2b(a.x) | ((unsigned int)f2b(b.x) << 16);
        u[1] = (unsigned int)f2b(a.y) | ((unsigned int)f2b(b.y) << 16);
        u[2] = (unsigned int)f2b(a.z) | ((unsigned int)f2b(b.z) << 16);
        u[3] = (unsigned int)f2b(a.w) | ((unsigned int)f2b(b.w) << 16);
        const int sw = ((rp >> 2) & 7) << 2;
        *(uint4*)&U[rp * 128 + (cu ^ sw)] = *(const uint4*)u;
    }
    __syncthreads();
    // ---- phase 2
    const int cc  = t >> 4;         // 0..15
    const int ch0 = t & 15;
#pragma unroll
    for (int s = 0; s < 8; ++s) {
        const int c = s * 16 + cc;  // output row (source col) 0..127
#pragma unroll
        for (int hh = 0; hh < 2; ++hh) {
            const int chunk = ch0 + hh * 16;        // 0..31 (8 src rows each)
            const int sw = (chunk & 7) << 2;
            unsigned int u[4];
#pragma unroll
            for (int j = 0; j < 4; ++j)
                u[j] = U[(chunk * 4 + j) * 128 + (c ^ sw)];
            *(int4*)(dst + (size_t)(C0 + c) * R + R0 + chunk * 8) = *(const int4*)u;
        }
    }
}

// ---------------- Dispatch A: gate (blocks 0..2047) + w1 transpose (1024) --
// w1 [e][1024][4096] -> W1T [e][4096][1024]: per expert 4 rb x 32 cb.
__global__ __launch_bounds__(256) void gate_fused(
    const float* __restrict__ x, const float* __restrict__ wg,
    float* __restrict__ gates8, int* __restrict__ token_expert,
    unsigned short* __restrict__ xb16,
    const float* __restrict__ w1, unsigned short* __restrict__ W1T)
{
    __shared__ unsigned int U[128 * 128];   // 64 KB
    const int b = blockIdx.x;
    if (b >= 2048) {
        const int i = b - 2048;             // 0..1023
        const int e = i >> 7, rem = i & 127;
        const int by = rem >> 5, bx = rem & 31;   // 4 x 32
        transpose_tile_lds(w1 + (size_t)e * MDIM * HDIM, W1T + (size_t)e * MDIM * HDIM,
                           MDIM, HDIM, by * 256, bx * 128, U);
        return;
    }

    const int wave = threadIdx.x >> 6, lane = threadIdx.x & 63;
    const int s = b * 4 + wave;

    const float* xr = x + (size_t)s * MDIM + lane * 16;
    float xv[16];
#pragma unroll
    for (int q = 0; q < 4; ++q) *(float4*)(xv + q * 4) = *(const float4*)(xr + q * 4);

    {
        unsigned short bv[16];
#pragma unroll
        for (int j = 0; j < 16; ++j) bv[j] = f2b(xv[j]);
        int4* dst = (int4*)(xb16 + (size_t)s * MDIM + lane * 16);
        dst[0] = ((const int4*)bv)[0];
        dst[1] = ((const int4*)bv)[1];
    }

    float acc[EXP];
#pragma unroll
    for (int e = 0; e < EXP; ++e) acc[e] = 0.f;
    const int m0 = lane * 16;
#pragma unroll
    for (int j = 0; j < 16; ++j) {
        const float xm = xv[j];
        const float* wr = wg + (size_t)(m0 + j) * EXP;
        float4 w0 = *(const float4*)(wr);
        float4 w1v = *(const float4*)(wr + 4);
        acc[0] += xm * w0.x; acc[1] += xm * w0.y; acc[2] += xm * w0.z; acc[3] += xm * w0.w;
        acc[4] += xm * w1v.x; acc[5] += xm * w1v.y; acc[6] += xm * w1v.z; acc[7] += xm * w1v.w;
    }
#pragma unroll
    for (int e = 0; e < EXP; ++e) {
#pragma unroll
        for (int off = 32; off > 0; off >>= 1)
            acc[e] += __shfl_down(acc[e], off);
    }
    if (lane == 0) {
        float mx = acc[0]; int idx = 0;
#pragma unroll
        for (int e = 1; e < EXP; ++e) if (acc[e] > mx) { mx = acc[e]; idx = e; }
        float g[EXP]; float sum = 0.f;
#pragma unroll
        for (int e = 0; e < EXP; ++e) { g[e] = expf(acc[e] - mx); sum += g[e]; }
        float inv = 1.f / sum;
#pragma unroll
        for (int e = 0; e < EXP; ++e) gates8[(size_t)s * EXP + e] = g[e] * inv;
        token_expert[s] = idx;
    }
}

// ---------------- Dispatch B: scan (block 0) + out-zero (1..2048) + w2T ----
// w2 [e][4096][1024] -> W2T [e][1024][4096]: per expert 16 rb x 8 cb.
__global__ __launch_bounds__(256) void mega_prep(
    const float* __restrict__ gates8, const int* __restrict__ token_expert,
    int* __restrict__ slot_token, float* __restrict__ slot_gate,
    float* __restrict__ laux_out,
    const float* __restrict__ w2, unsigned short* __restrict__ W2T,
    float* __restrict__ outz)
{
    __shared__ int          cntS[256 * EXP];    // 8 KB
    __shared__ float        fsumS[256 * EXP];   // 8 KB
    __shared__ unsigned int U[128 * 128];       // 64 KB

    const int b = blockIdx.x;
    const int t = threadIdx.x;

    if (b == 0) {
        // ---------------- scan ----------------
        for (int i = t; i < EXP * CAP; i += 256) slot_token[i] = -1;

        int local[EXP];
#pragma unroll
        for (int e = 0; e < EXP; ++e) local[e] = 0;
        const int s0 = t * 32;
        for (int j = 0; j < 32; ++j) local[token_expert[s0 + j]]++;

        int incl[EXP];
#pragma unroll
        for (int e = 0; e < EXP; ++e) { incl[e] = local[e]; cntS[t * EXP + e] = incl[e]; }
        __syncthreads();
        // Hillis-Steele inclusive scan over 256 entries (8 steps)
        for (int d = 1; d < 256; d <<= 1) {
            int add[EXP];
            if (t >= d) {
#pragma unroll
                for (int e = 0; e < EXP; ++e) add[e] = cntS[(t - d) * EXP + e];
            }
            __syncthreads();
            if (t >= d) {
#pragma unroll
                for (int e = 0; e < EXP; ++e) { incl[e] += add[e]; cntS[t * EXP + e] = incl[e]; }
            }
            __syncthreads();
        }

        int off[EXP];
#pragma unroll
        for (int e = 0; e < EXP; ++e) off[e] = incl[e] - local[e];
        for (int j = 0; j < 32; ++j) {
            int s = s0 + j;
            int e = token_expert[s];
            int loc = off[e]++;
            if (loc < CAP) {
                int slot = e * CAP + loc;
                slot_token[slot] = s;
                slot_gate[slot]  = gates8[(size_t)s * EXP + e];
            }
        }

        float ms[EXP];
#pragma unroll
        for (int e = 0; e < EXP; ++e) ms[e] = 0.f;
        for (int j = 0; j < 32; ++j) {
            const float* g = gates8 + (size_t)(s0 + j) * EXP;
#pragma unroll
            for (int e = 0; e < EXP; ++e) ms[e] += g[e];
        }
#pragma unroll
        for (int e = 0; e < EXP; ++e) fsumS[t * EXP + e] = ms[e];
        __syncthreads();
        for (int st = 128; st > 0; st >>= 1) {
            if (t < st) {
#pragma unroll
                for (int e = 0; e < EXP; ++e) fsumS[t * EXP + e] += fsumS[(t + st) * EXP + e];
            }
            __syncthreads();
        }
        if (t == 0) {
            float l = 0.f;
#pragma unroll
            for (int e = 0; e < EXP; ++e)
                l += (fsumS[e] / (float)S_TOK) * ((float)cntS[255 * EXP + e] / (float)S_TOK);
            laux_out[0] = l * (float)EXP;
        }
        return;
    }

    if (b <= 2048) {
        // ---------------- zero out ----------------
        float4* p = (float4*)(outz + (size_t)(b - 1) * 4096 + t * 16);
        const float4 z = {0.f, 0.f, 0.f, 0.f};
        p[0] = z; p[1] = z; p[2] = z; p[3] = z;
        return;
    }

    // ---------------- w2 transpose ----------------
    const int i = b - 2049;                 // 0..1023
    const int e = i >> 7, rem = i & 127;
    const int by = rem >> 3, bx = rem & 7;  // 16 x 8
    transpose_tile_lds(w2 + (size_t)e * MDIM * HDIM, W2T + (size_t)e * MDIM * HDIM,
                       HDIM, MDIM, by * 256, bx * 128, U);
}

// ---------------- standalone LDS transpose (narrow-ws mid path) ------------
__global__ __launch_bounds__(256) void transpose_lds_k(
    const float* __restrict__ src, unsigned short* __restrict__ dst,
    int R, int C, int cb)
{
    __shared__ unsigned int U[128 * 128];
    const int i = blockIdx.x;
    const int pe = (R / 256) * cb;
    const int e = i / pe, rem = i % pe;
    const int by = rem / cb, bx = rem % cb;
    transpose_tile_lds(src + (size_t)e * R * C, dst + (size_t)e * R * C,
                       R, C, by * 256, bx * 128, U);
}

// ============ pipelined expert GEMM (T1+T2+T3+T4+T5), 2 phases/tile ========
// out[CAP, N] = A[CAP, K] @ BT[N, K]^T per expert (blockIdx.z), bf16 MFMA.
// BM=256 BN=128 BK=64, 512 threads (8 waves as 2M x 4N), per-wave out 128x32.
// 3-deep LDS tile ring (144 KiB dynamic): tile t+2 staged into buffer freed
// by tile t-1 -> counted vmcnt(6) once per tile, never 0 in main loop.
// 2 phases/tile, 16 MFMA per phase (m201 cluster size).
// T2 swizzle: k-slot ^= row&7 via pre-swizzled global source (linear glds
// dest) + swizzled ds_read (rule 21).
template<int KT, int N, bool SCATTER, bool GATHER>
__global__ __launch_bounds__(512, 2) void ffn_gemm_8p(
    const unsigned short* __restrict__ Ag, const unsigned short* __restrict__ BT,
    void* __restrict__ Outv,
    const int* __restrict__ slot_token, const float* __restrict__ slot_gate)
{
    constexpr int K   = KT * 64;
    constexpr int NBX = N / 128;
    constexpr int NWG = NBX * (CAP / 256);   // per-expert x-grid; NWG%8==0

    extern __shared__ __align__(16) unsigned short sm[];
    unsigned short* Abuf = sm;               // 3 * 16384 ushorts (96 KiB)
    unsigned short* Bbuf = sm + 3 * 16384;   // 3 *  8192 ushorts (48 KiB)

    const int e    = blockIdx.z;
    const int orig = blockIdx.x;
    // T1: bijective XCD swizzle (NWG divisible by 8)
    const int logical = (orig & 7) * (NWG >> 3) + (orig >> 3);
    const int nb = (logical % NBX) * 128;
    const int ib = (logical / NBX) * 256;

    const int tid  = threadIdx.x;
    const int lane = tid & 63, wave = tid >> 6;
    const int quad = lane >> 4, l15 = lane & 15;
    const int wm = wave >> 2, wn = wave & 3;

    const int rr   = tid >> 3;                 // row within chunk (0..63)
    const int slot = (tid & 7) ^ (rr & 7);     // logical k-slot (8 bf16 each)

    const unsigned short* sA0;
    const unsigned short* sA1;
    const unsigned short* sA2;
    const unsigned short* sA3;
    if (GATHER) {
        const int base = e * CAP + ib + rr;
        int t0 = slot_token[base];
        int t1 = slot_token[base + 64];
        int t2 = slot_token[base + 128];
        int t3 = slot_token[base + 192];
        sA0 = Ag + (size_t)(t0 < 0 ? 0 : t0) * K + slot * 8;
        sA1 = Ag + (size_t)(t1 < 0 ? 0 : t1) * K + slot * 8;
        sA2 = Ag + (size_t)(t2 < 0 ? 0 : t2) * K + slot * 8;
        sA3 = Ag + (size_t)(t3 < 0 ? 0 : t3) * K + slot * 8;
    } else {
        sA0 = Ag + (size_t)(e * CAP + ib + rr) * K + slot * 8;
        sA1 = sA0 + (size_t)64 * K;
        sA2 = sA0 + (size_t)128 * K;
        sA3 = sA0 + (size_t)192 * K;
    }
    const unsigned short* Bsrc = BT + ((size_t)e * N + nb + rr) * K + slot * 8;

    auto stageA = [&](int buf, int t, const unsigned short* s, int ca) {
        gl2lds16(s + t * 64, Abuf + buf * 16384 + ca * 4096 + wave * 512);
    };
    auto stageB = [&](int buf, int t, int cb) {
        gl2lds16(Bsrc + (size_t)cb * 64 * K + t * 64,
                 Bbuf + buf * 8192 + cb * 4096 + wave * 512);
    };

    const int sx  = l15 & 7;
    const int ko0 = ((0 + quad) ^ sx) * 8;
    const int ko1 = ((4 + quad) ^ sx) * 8;
    const int arow = wm * 128 + l15;
    const int brow = wn * 32 + l15;

    floatx4 acc[8][2];
#pragma unroll
    for (int i = 0; i < 8; ++i)
#pragma unroll
        for (int j = 0; j < 2; ++j)
            acc[i][j] = (floatx4){0.f, 0.f, 0.f, 0.f};

    stageA(0, 0, sA0, 0); stageA(0, 0, sA1, 1); stageA(0, 0, sA2, 2); stageA(0, 0, sA3, 3);
    stageB(0, 0, 0); stageB(0, 0, 1);
    stageA(1, 1, sA0, 0); stageA(1, 1, sA1, 1); stageA(1, 1, sA2, 2); stageA(1, 1, sA3, 3);
    stageB(1, 1, 0); stageB(1, 1, 1);
    WAITV6();
    BARRIER();

    int buf = 0;
    for (int t = 0; t < KT; ++t) {
        const int nbuf = (buf >= 1) ? buf - 1 : 2;   // (buf+2)%3
        const bool st  = (t + 2 < KT);

        // ---------- phase A: read B(all)+A-half0; stage A0-A3; MFMA m0 (16)
        short8 brg[2][2];
#pragma unroll
        for (int fn = 0; fn < 2; ++fn) {
            const int row = brow + fn * 16;
            brg[fn][0] = *(const short8*)&Bbuf[buf * 8192 + row * 64 + ko0];
            brg[fn][1] = *(const short8*)&Bbuf[buf * 8192 + row * 64 + ko1];
        }
        short8 aA[8];
#pragma unroll
        for (int fm = 0; fm < 4; ++fm) {
            const int row = arow + fm * 16;
            aA[fm * 2 + 0] = *(const short8*)&Abuf[buf * 16384 + row * 64 + ko0];
            aA[fm * 2 + 1] = *(const short8*)&Abuf[buf * 16384 + row * 64 + ko1];
        }
        if (st) {
            stageA(nbuf, t + 2, sA0, 0); stageA(nbuf, t + 2, sA1, 1);
            stageA(nbuf, t + 2, sA2, 2); stageA(nbuf, t + 2, sA3, 3);
        }
        BARRIER(); SCHEDB();
        __builtin_amdgcn_s_setprio(1);
#pragma unroll
        for (int fm = 0; fm < 4; ++fm) {
            acc[fm][0] = __builtin_amdgcn_mfma_f32_16x16x32_bf16(aA[fm*2+0], brg[0][0], acc[fm][0], 0, 0, 0);
            acc[fm][0] = __builtin_amdgcn_mfma_f32_16x16x32_bf16(aA[fm*2+1], brg[0][1], acc[fm][0], 0, 0, 0);
            acc[fm][1] = __builtin_amdgcn_mfma_f32_16x16x32_bf16(aA[fm*2+0], brg[1][0], acc[fm][1], 0, 0, 0);
            acc[fm][1] = __builtin_amdgcn_mfma_f32_16x16x32_bf16(aA[fm*2+1], brg[1][1], acc[fm][1], 0, 0, 0);
        }
        __builtin_amdgcn_s_setprio(0); SCHEDB(); BARRIER();

        // ---------- phase B: read A-half1; stage B0,B1; MFMA m1 (16)
        short8 aB[8];
#pragma unroll
        for (int fm = 0; fm < 4; ++fm) {
            const int row = arow + 64 + fm * 16;
            aB[fm * 2 + 0] = *(const short8*)&Abuf[buf * 16384 + row * 64 + ko0];
            aB[fm * 2 + 1] = *(const short8*)&Abuf[buf * 16384 + row * 64 + ko1];
        }
        if (st) { stageB(nbuf, t + 2, 0); stageB(nbuf, t + 2, 1); }
        BARRIER(); SCHEDB();
        __builtin_amdgcn_s_setprio(1);
#pragma unroll
        for (int fm = 0; fm < 4; ++fm) {
            acc[4+fm][0] = __builtin_amdgcn_mfma_f32_16x16x32_bf16(aB[fm*2+0], brg[0][0], acc[4+fm][0], 0, 0, 0);
            acc[4+fm][0] = __builtin_amdgcn_mfma_f32_16x16x32_bf16(aB[fm*2+1], brg[0][1], acc[4+fm][0], 0, 0, 0);
            acc[4+fm][1] = __builtin_amdgcn_mfma_f32_16x16x32_bf16(aB[fm*2+0], brg[1][0], acc[4+fm][1], 0, 0, 0);
            acc[4+fm][1] = __builtin_amdgcn_mfma_f32_16x16x32_bf16(aB[fm*2+1], brg[1][1], acc[4+fm][1], 0, 0, 0);
        }
        __builtin_amdgcn_s_setprio(0); SCHEDB();
        if (t + 1 < KT) {
            if (st) WAITV6(); else WAITV0();
            BARRIER();
        }
        buf = (buf == 2) ? 0 : buf + 1;
    }

    // ---- epilogue: C/D layout col=lane&15, row=quad*4+reg
#pragma unroll
    for (int FM = 0; FM < 8; ++FM) {
        const int rowb = ib + wm * 128 + FM * 16 + quad * 4;
#pragma unroll
        for (int r = 0; r < 4; ++r) {
            const int gi = rowb + r;
            if (SCATTER) {
                const int slotI = e * CAP + gi;
                const int tok = slot_token[slotI];
                if (tok >= 0) {
                    const float gsc = slot_gate[slotI];
                    float* Out = (float*)Outv;
#pragma unroll
                    for (int fn = 0; fn < 2; ++fn) {
                        const int gn = nb + wn * 32 + fn * 16 + l15;
                        Out[(size_t)tok * N + gn] = gsc * acc[FM][fn][r];
                    }
                }
            } else {
                unsigned short* Out = (unsigned short*)Outv;
#pragma unroll
                for (int fn = 0; fn < 2; ++fn) {
                    const int gn = nb + wn * 32 + fn * 16 + l15;
                    Out[((size_t)e * CAP + gi) * N + gn] = f2b(fmaxf(acc[FM][fn][r], 0.f));
                }
            }
        }
    }
}

// ---------------- Kernel 2 (fallback): scan / slot assignment / l_aux ------
__global__ __launch_bounds__(256) void scan_kernel(
    const float* __restrict__ gates8, const int* __restrict__ token_expert,
    int* __restrict__ slot_token, float* __restrict__ slot_gate,
    float* __restrict__ laux_out)
{
    __shared__ int   cnt[256][EXP];
    __shared__ float fsum[256][EXP];
    __shared__ int   tot[EXP];
    const int t = threadIdx.x;

    for (int i = t; i < EXP * CAP; i += 256) slot_token[i] = -1;

    int local[EXP];
#pragma unroll
    for (int e = 0; e < EXP; ++e) local[e] = 0;
    const int s0 = t * 32;
    for (int j = 0; j < 32; ++j) local[token_expert[s0 + j]]++;
#pragma unroll
    for (int e = 0; e < EXP; ++e) cnt[t][e] = local[e];
    __syncthreads();

    if (t < EXP) {
        int run = 0;
        for (int i = 0; i < 256; ++i) { int v = cnt[i][t]; cnt[i][t] = run; run += v; }
        tot[t] = run;
    }
    __syncthreads();

    int off[EXP];
#pragma unroll
    for (int e = 0; e < EXP; ++e) off[e] = cnt[t][e];
    for (int j = 0; j < 32; ++j) {
        int s = s0 + j;
        int e = token_expert[s];
        int loc = off[e]++;
        if (loc < CAP) {
            int slot = e * CAP + loc;
            slot_token[slot] = s;
            slot_gate[slot]  = gates8[(size_t)s * EXP + e];
        }
    }

    float ms[EXP];
#pragma unroll
    for (int e = 0; e < EXP; ++e) ms[e] = 0.f;
    for (int j = 0; j < 32; ++j) {
        const float* g = gates8 + (size_t)(s0 + j) * EXP;
#pragma unroll
        for (int e = 0; e < EXP; ++e) ms[e] += g[e];
    }
#pragma unroll
    for (int e = 0; e < EXP; ++e) fsum[t][e] = ms[e];
    __syncthreads();
    for (int st = 128; st > 0; st >>= 1) {
        if (t < st) {
#pragma unroll
            for (int e = 0; e < EXP; ++e) fsum[t][e] += fsum[t + st][e];
        }
        __syncthreads();
    }
    if (t == 0) {
        float l = 0.f;
#pragma unroll
        for (int e = 0; e < EXP; ++e)
            l += (fsum[0][e] / (float)S_TOK) * ((float)tot[e] / (float)S_TOK);
        laux_out[0] = l * (float)EXP;
    }
}

// ---------------- Fallback (proven): fused-cvt GEMM ------------------------
template<int KSTEPS, int N, bool GATHER, bool SCATTER>
__global__ __launch_bounds__(256) void ffn_gemm_slow(
    const void* __restrict__ Agv, const float* __restrict__ Bg,
    void* __restrict__ Outv,
    const int* __restrict__ slot_token, const float* __restrict__ slot_gate)
{
    constexpr int K = KSTEPS * 32;
    const int e  = blockIdx.z;
    const int ib = blockIdx.y * 128;
    const int nb = blockIdx.x * 128;
    const int t  = threadIdx.x;

    __shared__ unsigned short As[128 * 40];
    __shared__ unsigned short Bs[32 * 136];

    const float* B = Bg + (size_t)e * K * N;
    const int arow  = t >> 1;
    const int ahalf = t & 1;
    const float* ArowF = nullptr;
    const unsigned short* ArowH = nullptr;
    bool avalid = true;
    if (GATHER) {
        int tok = slot_token[e * CAP + ib + arow];
        avalid = (tok >= 0);
        ArowF = (const float*)Agv + (size_t)(avalid ? tok : 0) * K;
    } else {
        ArowH = (const unsigned short*)Agv + ((size_t)e * CAP + ib + arow) * K;
    }
    const int bk  = t >> 3;
    const int bn0 = (t & 7) * 16;
    const float* Bptr = B + (size_t)bk * N + nb + bn0;

    const int lane = t & 63, wave = t >> 6;
    const int quad = lane >> 4, l15 = lane & 15;
    const int wr = wave >> 1, wc = wave & 1;

    floatx4 acc[4][4];
#pragma unroll
    for (int r = 0; r < 4; ++r)
#pragma unroll
        for (int c = 0; c < 4; ++c)
            acc[r][c] = (floatx4){0.f, 0.f, 0.f, 0.f};

    for (int kb = 0; kb < KSTEPS; ++kb) {
        const int k0 = kb * 32;
        unsigned short av[16];
        if (GATHER) {
            if (avalid) {
                const float4* p = (const float4*)(ArowF + k0 + ahalf * 16);
                float4 f0 = p[0], f1 = p[1], f2 = p[2], f3 = p[3];
                const float fa[16] = {f0.x,f0.y,f0.z,f0.w, f1.x,f1.y,f1.z,f1.w,
                                      f2.x,f2.y,f2.z,f2.w, f3.x,f3.y,f3.z,f3.w};
#pragma unroll
                for (int j = 0; j < 16; ++j) av[j] = f2b(fa[j]);
            } else {
#pragma unroll
                for (int j = 0; j < 16; ++j) av[j] = 0;
            }
        } else {
            const int4* p = (const int4*)(ArowH + k0 + ahalf * 16);
            *(int4*)(av)     = p[0];
            *(int4*)(av + 8) = p[1];
        }
        unsigned short bv[16];
        {
            const float4* q = (const float4*)(Bptr + (size_t)k0 * N);
            float4 f0 = q[0], f1 = q[1], f2 = q[2], f3 = q[3];
            const float fb[16] = {f0.x,f0.y,f0.z,f0.w, f1.x,f1.y,f1.z,f1.w,
                                  f2.x,f2.y,f2.z,f2.w, f3.x,f3.y,f3.z,f3.w};
#pragma unroll
            for (int j = 0; j < 16; ++j) bv[j] = f2b(fb[j]);
        }

        *(int4*)&As[arow * 40 + ahalf * 16]     = *(int4*)(av);
        *(int4*)&As[arow * 40 + ahalf * 16 + 8] = *(int4*)(av + 8);
        *(int4*)&Bs[bk * 136 + bn0]             = *(int4*)(bv);
        *(int4*)&Bs[bk * 136 + bn0 + 8]         = *(int4*)(bv + 8);
        __syncthreads();

        short8 af[4];
#pragma unroll
        for (int r = 0; r < 4; ++r)
            af[r] = *(const short8*)&As[(wr * 64 + r * 16 + l15) * 40 + quad * 8];
        short8 bfr[4];
#pragma unroll
        for (int c = 0; c < 4; ++c) {
#pragma unroll
            for (int j = 0; j < 8; ++j)
                bfr[c][j] = (short)Bs[(quad * 8 + j) * 136 + wc * 64 + c * 16 + l15];
        }
#pragma unroll
        for (int r = 0; r < 4; ++r)
#pragma unroll
            for (int c = 0; c < 4; ++c)
                acc[r][c] = __builtin_amdgcn_mfma_f32_16x16x32_bf16(af[r], bfr[c], acc[r][c], 0, 0, 0);
        __syncthreads();
    }

#pragma unroll
    for (int r = 0; r < 4; ++r) {
#pragma unroll
        for (int reg = 0; reg < 4; ++reg) {
            const int gi = ib + wr * 64 + r * 16 + quad * 4 + reg;
            if (SCATTER) {
                const int slot = e * CAP + gi;
                const int tok = slot_token[slot];
                if (tok >= 0) {
                    const float gsc = slot_gate[slot];
                    float* Out = (float*)Outv;
#pragma unroll
                    for (int c = 0; c < 4; ++c) {
                        const int gn = nb + wc * 64 + c * 16 + l15;
                        Out[(size_t)tok * N + gn] = gsc * acc[r][c][reg];
                    }
                }
            } else {
                unsigned short* Out = (unsigned short*)Outv;
#pragma unroll
                for (int c = 0; c < 4; ++c) {
                    const int gn = nb + wc * 64 + c * 16 + l15;
                    Out[((size_t)e * CAP + gi) * N + gn] = f2b(fmaxf(acc[r][c][reg], 0.f));
                }
            }
        }
    }
}

extern "C" void kernel_launch(void* const* d_in, const int* in_sizes, int n_in,
                              void* d_out, int out_size, void* d_ws, size_t ws_size,
                              hipStream_t stream)
{
    const float* x  = (const float*)d_in[0];   // [8192,1024] fp32
    const float* wg = (const float*)d_in[1];   // [1024,8]    fp32
    const float* w1 = (const float*)d_in[2];   // [8,1024,4096] fp32
    const float* w2 = (const float*)d_in[3];   // [8,4096,1024] fp32
    float* out = (float*)d_out;                // 8388608 out + 1 l_aux, fp32
    float* laux = out + (size_t)S_TOK * MDIM;

    char* ws = (char*)d_ws;
    float* gates8       = (float*)(ws);                 // 256 KB
    int*   token_expert = (int*)(ws + 262144);          // 32 KB
    int*   slot_token   = (int*)(ws + 294912);          // 32 KB
    float* slot_gate    = (float*)(ws + 327680);        // 32 KB
    unsigned short* xb16 = (unsigned short*)(ws + 360448);      // 16 MB
    unsigned short* h    = (unsigned short*)(ws + 17137664);    // 64 MB
    unsigned short* W1T  = (unsigned short*)(ws + 84246528);    // 64 MB
    unsigned short* W2T  = (unsigned short*)(ws + 151355392);   // 64 MB (wide only)

    const size_t FAST_NEED = 151355392ull;               // through W1T
    const size_t WIDE_NEED = 218464256ull;               // + W2T

    if (ws_size >= FAST_NEED) {
        const bool wide = (ws_size >= WIDE_NEED);

        static bool tried = false, ok8 = false;
        if (!tried) {
            tried = true;
            ok8 = (hipFuncSetAttribute((const void*)ffn_gemm_8p<16, HDIM, false, true>,
                       hipFuncAttributeMaxDynamicSharedMemorySize, 147456) == hipSuccess)
               && (hipFuncSetAttribute((const void*)ffn_gemm_8p<64, MDIM, true, false>,
                       hipFuncAttributeMaxDynamicSharedMemorySize, 147456) == hipSuccess);
        }

        // dispatch A: gate (2048 blocks) + w1 transpose (1024 blocks)
        gate_fused<<<dim3(3072), dim3(256), 0, stream>>>(
            x, wg, gates8, token_expert, xb16, w1, W1T);

        // dispatch B: scan + out-zero + w2 transpose (wide) in parallel
        const int nblk = 1 + 2048 + (wide ? 1024 : 0);
        mega_prep<<<dim3(nblk), dim3(256), 0, stream>>>(
            gates8, token_expert, slot_token, slot_gate, laux,
            w2, wide ? W2T : W1T, out);

        if (ok8) {
            ffn_gemm_8p<16, HDIM, false, true><<<dim3((HDIM/128)*(CAP/256), 1, EXP), dim3(512), 147456, stream>>>(
                xb16, W1T, h, slot_token, slot_gate);
            if (!wide)
                transpose_lds_k<<<dim3(1024), dim3(256), 0, stream>>>(w2, W1T, HDIM, MDIM, MDIM / 128);
            ffn_gemm_8p<64, MDIM, true, false><<<dim3((MDIM/128)*(CAP/256), 1, EXP), dim3(512), 147456, stream>>>(
                h, wide ? W2T : W1T, out, slot_token, slot_gate);
        } else {
            // proven fallback: fused-cvt GEMMs straight from fp32 weights
            ffn_gemm_slow<32, HDIM, true, false><<<dim3(HDIM / 128, CAP / 128, EXP), dim3(256), 0, stream>>>(
                x, w1, h, slot_token, slot_gate);
            ffn_gemm_slow<128, MDIM, false, true><<<dim3(MDIM / 128, CAP / 128, EXP), dim3(256), 0, stream>>>(
                h, w2, out, slot_token, slot_gate);
        }
    } else {
        hipMemsetAsync(d_out, 0, (size_t)out_size * 4, stream);
        gate_fused<<<dim3(2048), dim3(256), 0, stream>>>(
            x, wg, gates8, token_expert, xb16, w1, (unsigned short*)h);
        scan_kernel<<<dim3(1), dim3(256), 0, stream>>>(gates8, token_expert, slot_token, slot_gate, laux);
        unsigned short* hs = (unsigned short*)(ws + 360448);    // 64 MB
        ffn_gemm_slow<32, HDIM, true, false><<<dim3(HDIM / 128, CAP / 128, EXP), dim3(256), 0, stream>>>(
            x, w1, hs, slot_token, slot_gate);
        ffn_gemm_slow<128, MDIM, false, true><<<dim3(MDIM / 128, CAP / 128, EXP), dim3(256), 0, stream>>>(
            hs, w2, out, slot_token, slot_gate);
    }
}